// Round 7
// baseline (990.889 us; speedup 1.0000x reference)
//
#include <hip/hip_runtime.h>

#define T_ 512
#define N_ 60
#define F_ 2
#define C_ 64
#define H_ 512
#define IN_ 3840
#define FOURH 2048
#define PRED_SZ 61440
#define ADJ_SZ 1843200
#define K2_ 128    // padded reduced-K for the Wih2 GEMM (120 real + 8 zero)
#define LDSK 40    // padded LDS row stride in bf16 units (2-way conflicts only)
#define K3P 1152   // W3 K (=1028) padded to 32*4 multiple
#define SAS 520    // LDS stride for 512-col activation buffers (2-way conflicts)
#define SBS 1160   // LDS stride for 1152-col activation buffer (2-way conflicts)

typedef __attribute__((ext_vector_type(8))) short bf8;
typedef __attribute__((ext_vector_type(4))) float f4;

__device__ __forceinline__ unsigned short f2bf(float f)
{
    unsigned int u = __float_as_uint(f);
    u = (u + 0x7FFFu + ((u >> 16) & 1u)) >> 16;
    return (unsigned short)u;
}

// cast fp32 -> bf16 (weights, once per launch)
__global__ void cast_k(const float* src, unsigned short* dst, int n)
{
    int i = blockIdx.x * 256 + threadIdx.x;
    if (i < n) dst[i] = f2bf(src[i]);
}

// transpose + cast: src [K][Nc] fp32 -> dst [Nc][Kpad] bf16 (pad k>=K with 0)
__global__ __launch_bounds__(256) void castT_k(
    const float* src, unsigned short* dst, int K, int Nc, int Kpad)
{
    __shared__ float tile[32][33];
    int k0 = blockIdx.x * 32;
    int n0 = blockIdx.y * 32;
    int tx = threadIdx.x & 31;
    int ty = threadIdx.x >> 5;   // 0..7

    #pragma unroll
    for (int i = 0; i < 4; ++i) {
        int k = k0 + ty + i * 8;
        int n = n0 + tx;
        tile[ty + i * 8][tx] = (k < K && n < Nc) ? src[(long)k * Nc + n] : 0.0f;
    }
    __syncthreads();
    #pragma unroll
    for (int i = 0; i < 4; ++i) {
        int n = n0 + ty + i * 8;
        int k = k0 + tx;
        if (n < Nc && k < Kpad)
            dst[(long)n * Kpad + k] = f2bf(tile[tx][ty + i * 8]);
    }
}

// h (both ping-pong buffers) = 0, c = 0, out frame 0 = feature_input[0]
__global__ void init_k(unsigned short* h_bf, float* c, const float* feat, float* out)
{
    int i = blockIdx.x * 256 + threadIdx.x;   // 1024 blocks -> 262144
    h_bf[i] = 0;
    h_bf[i + 262144] = 0;   // second ping-pong buffer (contiguous)
    c[i] = 0.0f;
    if (i < PRED_SZ) out[i] = feat[i];
}

// ---------------------------------------------------------------------------
// Wih2[o, n*2+f] = sum_c Wih[o, n*64+c] * W[f,c]   (2048 x 120, pad to 128)
// biasAll[o] = bih[o] + bhh[o] + sum_k Wih[o,k]*b[k&63]
// ---------------------------------------------------------------------------
__global__ __launch_bounds__(256) void wih2_k(
    const float* Wih, const float* W, const float* b,
    const float* bih, const float* bhh,
    unsigned short* Wih2_bf, float* biasAll)
{
    __shared__ float row[IN_];     // 3840 floats
    __shared__ float wc[2][64];
    __shared__ float bb[64];
    __shared__ float red[256];

    int o = blockIdx.x;
    int tid = threadIdx.x;

    if (tid < 128) wc[tid >> 6][tid & 63] = W[tid];   // W is [2][64] row-major
    if (tid < 64) bb[tid] = b[tid];
    for (int k = tid; k < IN_; k += 256) row[k] = Wih[(long)o * IN_ + k];
    __syncthreads();

    if (tid < 128) {
        float s = 0.0f;
        if (tid < 120) {
            int n = tid >> 1;
            int f = tid & 1;
            for (int c = 0; c < 64; ++c) s += row[n * 64 + c] * wc[f][c];
        }
        Wih2_bf[(long)o * K2_ + tid] = f2bf(s);   // pad cols 120..127 = 0
    }

    float sb = 0.0f;
    for (int k = tid; k < IN_; k += 256) sb += row[k] * bb[k & 63];
    red[tid] = sb;
    __syncthreads();
    for (int s = 128; s > 0; s >>= 1) {
        if (tid < s) red[tid] += red[tid + s];
        __syncthreads();
    }
    if (tid == 0) biasAll[o] = bih[o] + bhh[o] + red[0];
}

// ---------------------------------------------------------------------------
// Encoder GCN (reduced): Y[t, n*2+f] = norm_n * sum_j A_nj * norm_j * x[j,f]
// blockIdx.x = frame*512 + t ; 128 threads. Output bf16 [row][128], pad = 0.
// ---------------------------------------------------------------------------
__global__ __launch_bounds__(128) void gcn_enc_y(
    const float* x, const float* adj, unsigned short* Y)
{
    __shared__ float sA[N_][N_];
    __shared__ float sx[N_][2];
    __shared__ float snorm[N_];

    int frame = blockIdx.x >> 9;
    int t = blockIdx.x & 511;
    const float* xf = x + (long)frame * PRED_SZ + (long)t * 120;
    const float* af = adj + (long)frame * ADJ_SZ + (long)t * 3600;
    int tid = threadIdx.x;

    for (int l = tid; l < N_ * N_; l += 128) {
        int i = l / N_;
        int j = l - i * N_;
        float a = af[l];
        if (i == j) a += 1.0f;
        sA[i][j] = a;
    }
    if (tid < 120) sx[tid >> 1][tid & 1] = xf[tid];
    __syncthreads();

    if (tid < N_) {
        float d = 0.0f;
        for (int j = 0; j < N_; ++j) d += sA[tid][j];
        snorm[tid] = (d > 0.0f) ? rsqrtf(d) : 0.0f;
    }
    __syncthreads();

    if (tid < 128) {
        float y = 0.0f;
        if (tid < 120) {
            int n = tid >> 1;
            int f = tid & 1;
            float s = 0.0f;
            for (int j = 0; j < N_; ++j) s += sA[n][j] * snorm[j] * sx[j][f];
            y = snorm[n] * s;
        }
        Y[(long)blockIdx.x * K2_ + tid] = f2bf(y);
    }
}

// ---------------------------------------------------------------------------
// Decoder GCN (reduced): radius graph from pred, then Y as above.
// ---------------------------------------------------------------------------
__global__ __launch_bounds__(128) void gcn_dec_y(
    const float* pred, const float* stdv, const float* meanv, unsigned short* Y)
{
    __shared__ float sA[N_][N_];
    __shared__ float sx[N_][2];   // raw pred (GCN features)
    __shared__ float dx0[N_];
    __shared__ float dx1[N_];
    __shared__ int sex[N_];
    __shared__ float snorm[N_];

    int t = blockIdx.x;
    int tid = threadIdx.x;
    const float* pr = pred + (long)t * 120;

    if (tid < 120) sx[tid >> 1][tid & 1] = pr[tid];
    if (tid < N_) {
        float vx = pr[tid * 2 + 0] * stdv[0] + meanv[0];
        float vy = pr[tid * 2 + 1] * stdv[1] + meanv[1];
        dx0[tid] = vx;
        dx1[tid] = vy;
        sex[tid] = (vx > 0.04f) && (vy > 0.04f);
    }
    __syncthreads();

    for (int l = tid; l < N_ * N_; l += 128) {
        int i = l / N_;
        int j = l - i * N_;
        float ddx = dx0[i] - dx0[j];
        float ddy = dx1[i] - dx1[j];
        float d = sqrtf(ddx * ddx + ddy * ddy);
        int conn = ((d > 0.0f) && (d < 10.0f)) || (i == j);
        float a = (sex[i] && sex[j] && conn) ? 1.0f : 0.0f;
        if (i == j) a += 1.0f;     // GCN self-loop on top of radius graph
        sA[i][j] = a;
    }
    __syncthreads();

    if (tid < N_) {
        float d = 0.0f;
        for (int j = 0; j < N_; ++j) d += sA[tid][j];
        snorm[tid] = (d > 0.0f) ? rsqrtf(d) : 0.0f;
    }
    __syncthreads();

    if (tid < 128) {
        float y = 0.0f;
        if (tid < 120) {
            int n = tid >> 1;
            int f = tid & 1;
            float s = 0.0f;
            for (int j = 0; j < N_; ++j) s += sA[n][j] * snorm[j] * sx[j][f];
            y = snorm[n] * s;
        }
        Y[(long)t * K2_ + tid] = f2bf(y);
    }
}

// ---------------------------------------------------------------------------
// 32x32-tile MFMA GEMM (BT=1: B stored [Nc][K]); mode 3: Cf = acc + bias1.
// ---------------------------------------------------------------------------
template<int BT>
__global__ __launch_bounds__(256) void gemm32(
    const unsigned short* Abf, const unsigned short* Bb,
    const float* bias1, float* Cf, unsigned short* Cbf,
    int M, int Nc, int K, int mode)
{
    __shared__ unsigned short As[32 * LDSK];
    __shared__ unsigned short Bs[32 * LDSK];

    int tid = threadIdx.x;
    int wave = tid >> 6;
    int wt = wave >> 1, wj = wave & 1;
    int lane = tid & 63;
    int quad = lane >> 4;
    int l16 = lane & 15;
    int row0 = blockIdx.y * 32;
    int col0 = blockIdx.x * 32;

    f4 acc = {0.f, 0.f, 0.f, 0.f};
    const ushort4 zu = make_ushort4(0, 0, 0, 0);

    int sr = tid >> 3;          // 0..31
    int sko = (tid & 7) * 4;    // 0..28

    auto loadA = [&](int k0, ushort4& v) {
        int gm = row0 + sr, gk = k0 + sko;
        v = zu;
        if (gm < M && gk + 4 <= K) v = *(const ushort4*)&Abf[(long)gm * K + gk];
    };
    auto loadB1 = [&](int k0, ushort4& v) {
        int gn = col0 + sr, gk = k0 + sko;
        v = zu;
        if (gn < Nc && gk + 4 <= K) v = *(const ushort4*)&Bb[(long)gn * K + gk];
    };

    ushort4 a0, b0, na0 = zu, nb0 = zu;
    loadA(0, a0);
    loadB1(0, b0);

    int niter = (K + 31) / 32;
    for (int it = 0; it < niter; ++it) {
        if (it + 1 < niter) {
            int kn = (it + 1) * 32;
            loadA(kn, na0);
            loadB1(kn, nb0);
        }
        *(ushort4*)&As[sr * LDSK + sko] = a0;
        *(ushort4*)&Bs[sr * LDSK + sko] = b0;
        __syncthreads();

        bf8 fa = *(const bf8*)&As[(wt * 16 + l16) * LDSK + quad * 8];
        bf8 fb = *(const bf8*)&Bs[(wj * 16 + l16) * LDSK + quad * 8];
        acc = __builtin_amdgcn_mfma_f32_16x16x32_bf16(fa, fb, acc, 0, 0, 0);
        __syncthreads();

        a0 = na0; b0 = nb0;
    }

    int gn = col0 + wj * 16 + l16;
    if (gn < Nc) {
        float bsv = bias1[gn];
        #pragma unroll
        for (int r = 0; r < 4; ++r) {
            int gm = row0 + wt * 16 + quad * 4 + r;
            if (gm >= M) continue;
            float v = acc[r] + bsv;
            long idx = (long)gm * Nc + gn;
            if (mode == 2) {
                if (v < 0.0f) v = 0.0f;
                Cbf[idx] = f2bf(v);
            } else {
                Cf[idx] = v;
            }
        }
    }
}

// ---------------------------------------------------------------------------
// Fused h@Whh^T + LSTM pointwise, 256 blocks (proven round 5).
// ---------------------------------------------------------------------------
__global__ __launch_bounds__(256) void whh_lstm_k(
    const unsigned short* hprev, const unsigned short* Whh_bf,
    const float* pregates, float* c, unsigned short* hnew)
{
    __shared__ unsigned short As[32 * LDSK];
    __shared__ unsigned short Bs[128 * LDSK];

    int tid = threadIdx.x;
    int wave = tid >> 6;
    int wt = wave >> 1, wj = wave & 1;
    int lane = tid & 63;
    int quad = lane >> 4;
    int l16 = lane & 15;
    int j0 = blockIdx.x * 32;
    int row0 = blockIdx.y * 32;

    int sr = tid >> 3;
    int sko = (tid & 7) * 4;
    int br = tid >> 1;
    int bko = (tid & 1) * 16;
    long browbase = (long)((br >> 5) * H_ + j0 + (br & 31)) * H_;

    f4 acc[4];
    #pragma unroll
    for (int g = 0; g < 4; ++g) acc[g] = f4{0.f, 0.f, 0.f, 0.f};

    ushort4 pa, npa = make_ushort4(0, 0, 0, 0);
    uint4 pb0, pb1, npb0 = uint4{0,0,0,0}, npb1 = uint4{0,0,0,0};

    pa  = *(const ushort4*)&hprev[(long)(row0 + sr) * H_ + sko];
    pb0 = *(const uint4*)&Whh_bf[browbase + bko];
    pb1 = *(const uint4*)&Whh_bf[browbase + bko + 8];

    for (int k0 = 0; k0 < H_; k0 += 32) {
        int kn = k0 + 32;
        if (kn < H_) {
            npa  = *(const ushort4*)&hprev[(long)(row0 + sr) * H_ + kn + sko];
            npb0 = *(const uint4*)&Whh_bf[browbase + kn + bko];
            npb1 = *(const uint4*)&Whh_bf[browbase + kn + bko + 8];
        }
        *(ushort4*)&As[sr * LDSK + sko] = pa;
        *(uint4*)&Bs[br * LDSK + bko]     = pb0;
        *(uint4*)&Bs[br * LDSK + bko + 8] = pb1;
        __syncthreads();

        bf8 fa = *(const bf8*)&As[(wt * 16 + l16) * LDSK + quad * 8];
        #pragma unroll
        for (int g = 0; g < 4; ++g) {
            bf8 fb = *(const bf8*)&Bs[(g * 32 + wj * 16 + l16) * LDSK + quad * 8];
            acc[g] = __builtin_amdgcn_mfma_f32_16x16x32_bf16(fa, fb, acc[g], 0, 0, 0);
        }
        __syncthreads();

        pa = npa; pb0 = npb0; pb1 = npb1;
    }

    int j = j0 + wj * 16 + l16;
    #pragma unroll
    for (int r = 0; r < 4; ++r) {
        int t = row0 + wt * 16 + quad * 4 + r;
        const float* pg = pregates + (long)t * FOURH;
        float gi = pg[j]        + acc[0][r];
        float gf = pg[512 + j]  + acc[1][r];
        float gg = pg[1024 + j] + acc[2][r];
        float go = pg[1536 + j] + acc[3][r];
        float ig = 1.0f / (1.0f + expf(-gi));
        float fg = 1.0f / (1.0f + expf(-gf));
        float g2 = tanhf(gg);
        float og = 1.0f / (1.0f + expf(-go));
        long ci = (long)t * H_ + j;
        float cn = fg * c[ci] + ig * g2;
        c[ci] = cn;
        hnew[ci] = f2bf(og * tanhf(cn));
    }
}

// ---------------------------------------------------------------------------
// Fused MLP: relu chain 512->512->1028->512->120 for 16 rows per block.
// Weights pre-transposed [Nc][Kpad] bf16; B-fragments loaded straight from
// global (L2-resident), 4-deep prefetch. Invalid-col lanes clamp their weight
// row; only the epilogue write is guarded (garbage stays in that lane's D col).
// ---------------------------------------------------------------------------
template<int TO_LDS>
__device__ __forceinline__ void mlp_layer(
    const unsigned short* inL, int inStride,
    const unsigned short* __restrict__ Wt, int Kld,
    const float* __restrict__ bias, int Nc,
    unsigned short* outL, int outStride,
    float* outG, int outGs, int row0,
    int wave, int quad, int l16)
{
    int nk = Kld >> 5;
    for (int nc0 = 0; nc0 < Nc; nc0 += 64) {
        int n = nc0 + wave * 16 + l16;
        int vn = (n < Nc);
        int nc = vn ? n : (Nc - 1);
        const unsigned short* wp = Wt + (long)nc * Kld + quad * 8;
        const unsigned short* ip = inL + l16 * inStride + quad * 8;
        f4 acc = {0.f, 0.f, 0.f, 0.f};
        bf8 f0 = *(const bf8*)(wp);
        bf8 f1 = *(const bf8*)(wp + 32);
        bf8 f2 = *(const bf8*)(wp + 64);
        bf8 f3 = *(const bf8*)(wp + 96);
        for (int ks = 0; ks + 4 <= nk; ks += 4) {
            bf8 fa0 = *(const bf8*)(ip + (ks + 0) * 32);
            acc = __builtin_amdgcn_mfma_f32_16x16x32_bf16(fa0, f0, acc, 0, 0, 0);
            if (ks + 4 < nk) f0 = *(const bf8*)(wp + (ks + 4) * 32);
            bf8 fa1 = *(const bf8*)(ip + (ks + 1) * 32);
            acc = __builtin_amdgcn_mfma_f32_16x16x32_bf16(fa1, f1, acc, 0, 0, 0);
            if (ks + 5 < nk) f1 = *(const bf8*)(wp + (ks + 5) * 32);
            bf8 fa2 = *(const bf8*)(ip + (ks + 2) * 32);
            acc = __builtin_amdgcn_mfma_f32_16x16x32_bf16(fa2, f2, acc, 0, 0, 0);
            if (ks + 6 < nk) f2 = *(const bf8*)(wp + (ks + 6) * 32);
            bf8 fa3 = *(const bf8*)(ip + (ks + 3) * 32);
            acc = __builtin_amdgcn_mfma_f32_16x16x32_bf16(fa3, f3, acc, 0, 0, 0);
            if (ks + 7 < nk) f3 = *(const bf8*)(wp + (ks + 7) * 32);
        }
        float bv = bias[nc];
        #pragma unroll
        for (int r = 0; r < 4; ++r) {
            int m = quad * 4 + r;
            float v = acc[r] + bv;
            if (TO_LDS) {
                if (vn) {
                    if (v < 0.0f) v = 0.0f;
                    outL[m * outStride + n] = f2bf(v);
                }
            } else {
                if (vn) outG[(long)(row0 + m) * outGs + n] = v;
            }
        }
    }
}

__global__ __launch_bounds__(256) void mlp_k(
    const unsigned short* h,
    const unsigned short* W1t, const float* b1,
    const unsigned short* W2t, const float* b2,
    const unsigned short* W3t, const float* b3,
    const unsigned short* W4t, const float* b4,
    float* pred)
{
    __shared__ __attribute__((aligned(16))) unsigned short S1[16 * SAS];
    __shared__ __attribute__((aligned(16))) unsigned short S2[16 * SAS];
    __shared__ __attribute__((aligned(16))) unsigned short SB[16 * SBS];

    int tid = threadIdx.x;
    int wave = tid >> 6;
    int lane = tid & 63;
    int quad = lane >> 4;
    int l16 = lane & 15;
    int row0 = blockIdx.x * 16;

    // stage h rows (16 x 512 bf16) into S1: each thread moves 32 bf16 (4x uint4)
    {
        int r = tid >> 4;
        int co = (tid & 15) * 32;
        const uint4* src = (const uint4*)&h[(long)(row0 + r) * H_ + co];
        uint4 v0 = src[0], v1 = src[1], v2 = src[2], v3 = src[3];
        uint4* d = (uint4*)&S1[r * SAS + co];
        d[0] = v0; d[1] = v1; d[2] = v2; d[3] = v3;
    }
    // zero SB pad cols 1028..1151 (read as zeros in layer-3 K loop)
    for (int i = tid; i < 16 * 124; i += 256) {
        int rr = i / 124, cc = 1028 + i - (i / 124) * 124;
        SB[rr * SBS + cc] = 0;
    }
    __syncthreads();

    mlp_layer<1>(S1, SAS, W1t, 512, b1, 512, S2, SAS, (float*)0, 0, row0, wave, quad, l16);
    __syncthreads();
    mlp_layer<1>(S2, SAS, W2t, 512, b2, 1028, SB, SBS, (float*)0, 0, row0, wave, quad, l16);
    __syncthreads();
    mlp_layer<1>(SB, SBS, W3t, K3P, b3, 512, S1, SAS, (float*)0, 0, row0, wave, quad, l16);
    __syncthreads();
    mlp_layer<0>(S1, SAS, W4t, 512, b4, 120, (unsigned short*)0, 0, pred, 120, row0, wave, quad, l16);
}

extern "C" void kernel_launch(void* const* d_in, const int* in_sizes, int n_in,
                              void* d_out, int out_size, void* d_ws, size_t ws_size,
                              hipStream_t stream)
{
    const float* feat  = (const float*)d_in[0];
    const float* adjin = (const float*)d_in[1];
    const float* stdv  = (const float*)d_in[2];
    const float* meanv = (const float*)d_in[3];
    const float* gcnW  = (const float*)d_in[4];
    const float* gcnb  = (const float*)d_in[5];
    const float* Wih   = (const float*)d_in[6];
    const float* Whh   = (const float*)d_in[7];
    const float* bih   = (const float*)d_in[8];
    const float* bhh   = (const float*)d_in[9];
    const float* W1    = (const float*)d_in[10];
    const float* b1    = (const float*)d_in[11];
    const float* W2    = (const float*)d_in[12];
    const float* b2    = (const float*)d_in[13];
    const float* W3    = (const float*)d_in[14];
    const float* b3    = (const float*)d_in[15];
    const float* W4    = (const float*)d_in[16];
    const float* b4    = (const float*)d_in[17];
    float* out = (float*)d_out;

    int five = (ws_size >= (size_t)31400000u) ? 1 : 0;
    int slots = five ? 5 : 1;

    float* gates   = (float*)d_ws;                       // slots * 1,048,576 f
    float* c       = gates + (long)slots * 1048576;      // 262,144 f
    float* biasAll = c + 262144;                         // 2,048 f
    unsigned short* Y       = (unsigned short*)(biasAll + 2048);  // 5*65,536 us
    unsigned short* h1_bf   = Y + 5 * 65536;             // 262,144
    unsigned short* h2_bf   = h1_bf + 262144;            // 262,144
    unsigned short* Whh_bf  = h2_bf + 262144;            // 1,048,576
    unsigned short* W1t     = Whh_bf + 1048576;          // 262,144
    unsigned short* W2t     = W1t + 262144;              // 526,336 (1028*512)
    unsigned short* W3t     = W2t + 526336;              // 589,824 (512*1152)
    unsigned short* W4t     = W3t + 589824;              // 61,440  (120*512)
    unsigned short* Wih2_bf = W4t + 61440;               // 262,144

    // weight preprocessing (graph-safe: identical work every call)
    cast_k<<<(1048576 + 255) / 256, 256, 0, stream>>>(Whh, Whh_bf, 1048576);
    castT_k<<<dim3(16, 16), 256, 0, stream>>>(W1, W1t, 512, 512, 512);
    castT_k<<<dim3(16, 33), 256, 0, stream>>>(W2, W2t, 512, 1028, 512);
    castT_k<<<dim3(36, 16), 256, 0, stream>>>(W3, W3t, 1028, 512, K3P);
    castT_k<<<dim3(16, 4), 256, 0, stream>>>(W4, W4t, 512, 120, 512);
    wih2_k<<<FOURH, 256, 0, stream>>>(Wih, gcnW, gcnb, bih, bhh, Wih2_bf, biasAll);

    init_k<<<1024, 256, 0, stream>>>(h1_bf, c, feat, out);

    // all 5 encoder frames' reduced GCN in one launch
    gcn_enc_y<<<5 * T_, 128, 0, stream>>>(feat, adjin, Y);
    if (five)   // batched pre-gates for all encoder steps: [2560,128] @ Wih2^T
        gemm32<1><<<dim3(64, 80), 256, 0, stream>>>(Y, Wih2_bf, biasAll,
                                                    gates, (unsigned short*)0,
                                                    5 * T_, FOURH, K2_, 3);

    for (int step = 0; step < 7; ++step) {
        float* gs;
        if (step < 5) {
            if (five) {
                gs = gates + (long)step * 1048576;
            } else {
                gs = gates;
                gemm32<1><<<dim3(64, 16), 256, 0, stream>>>(Y + (long)step * 65536,
                                                            Wih2_bf, biasAll,
                                                            gs, (unsigned short*)0,
                                                            T_, FOURH, K2_, 3);
            }
        } else {
            gs = gates;   // slot 0 free after step 0
            gcn_dec_y<<<T_, 128, 0, stream>>>(out + (long)step * PRED_SZ,
                                              stdv, meanv, Y);
            gemm32<1><<<dim3(64, 16), 256, 0, stream>>>(Y, Wih2_bf, biasAll,
                                                        gs, (unsigned short*)0,
                                                        T_, FOURH, K2_, 3);
        }

        unsigned short* hp = (step & 1) ? h2_bf : h1_bf;
        unsigned short* hn = (step & 1) ? h1_bf : h2_bf;
        whh_lstm_k<<<dim3(16, 16), 256, 0, stream>>>(hp, Whh_bf, gs, c, hn);

        // fused MLP: h -> 512 -> 1028 -> 512 -> 120, pred -> out frame
        mlp_k<<<32, 256, 0, stream>>>(hn, W1t, b1, W2t, b2, W3t, b3, W4t, b4,
                                      out + (long)(step + 1) * PRED_SZ);
    }
}

// Round 9
// 575.421 us; speedup vs baseline: 1.7220x; 1.7220x over previous
//
#include <hip/hip_runtime.h>

#define T_ 512
#define N_ 60
#define F_ 2
#define C_ 64
#define H_ 512
#define IN_ 3840
#define FOURH 2048
#define PRED_SZ 61440
#define ADJ_SZ 1843200
#define K2_ 128    // padded reduced-K for the Wih2 GEMM (120 real + 8 zero)
#define LDSK 40    // padded LDS row stride in bf16 units (2-way conflicts only)

typedef __attribute__((ext_vector_type(8))) short bf8;
typedef __attribute__((ext_vector_type(4))) float f4;

__device__ __forceinline__ unsigned short f2bf(float f)
{
    unsigned int u = __float_as_uint(f);
    u = (u + 0x7FFFu + ((u >> 16) & 1u)) >> 16;
    return (unsigned short)u;
}

// merged fp32 -> bf16 weight casts (one launch); segment ladder on flat index
__global__ void prep_cast_k(const float* Whh, const float* W1, const float* W2,
                            const float* W3, const float* W4,
                            unsigned short* Whh_bf, unsigned short* W1_bf,
                            unsigned short* W2_bf, unsigned short* W3_bf,
                            unsigned short* W4_bf)
{
    long i = (long)blockIdx.x * 256 + threadIdx.x;   // 9472 blocks = 2,424,832
    if (i < 1048576) { Whh_bf[i] = f2bf(Whh[i]); return; }
    i -= 1048576;
    if (i < 262144) { W1_bf[i] = f2bf(W1[i]); return; }
    i -= 262144;
    if (i < 526336) { W2_bf[i] = f2bf(W2[i]); return; }
    i -= 526336;
    if (i < 526336) { W3_bf[i] = f2bf(W3[i]); return; }
    i -= 526336;
    W4_bf[i] = f2bf(W4[i]);
}

// h (both ping-pong buffers) = 0, c = 0, out frame 0 = feature_input[0]
__global__ void init_k(unsigned short* h_bf, float* c, const float* feat, float* out)
{
    int i = blockIdx.x * 256 + threadIdx.x;   // 1024 blocks -> 262144
    h_bf[i] = 0;
    h_bf[i + 262144] = 0;   // second ping-pong buffer (contiguous)
    c[i] = 0.0f;
    if (i < PRED_SZ) out[i] = feat[i];
}

// ---------------------------------------------------------------------------
// Wih2[o, n*2+f] = sum_c Wih[o, n*64+c] * W[f,c]   (2048 x 120, pad to 128)
// biasAll[o] = bih[o] + bhh[o] + sum_k Wih[o,k]*b[k&63]
// ---------------------------------------------------------------------------
__global__ __launch_bounds__(256) void wih2_k(
    const float* Wih, const float* W, const float* b,
    const float* bih, const float* bhh,
    unsigned short* Wih2_bf, float* biasAll)
{
    __shared__ float row[IN_];     // 3840 floats
    __shared__ float wc[2][64];
    __shared__ float bb[64];
    __shared__ float red[256];

    int o = blockIdx.x;
    int tid = threadIdx.x;

    if (tid < 128) wc[tid >> 6][tid & 63] = W[tid];   // W is [2][64] row-major
    if (tid < 64) bb[tid] = b[tid];
    for (int k = tid; k < IN_; k += 256) row[k] = Wih[(long)o * IN_ + k];
    __syncthreads();

    if (tid < 128) {
        float s = 0.0f;
        if (tid < 120) {
            int n = tid >> 1;
            int f = tid & 1;
            for (int c = 0; c < 64; ++c) s += row[n * 64 + c] * wc[f][c];
        }
        Wih2_bf[(long)o * K2_ + tid] = f2bf(s);   // pad cols 120..127 = 0
    }

    float sb = 0.0f;
    for (int k = tid; k < IN_; k += 256) sb += row[k] * bb[k & 63];
    red[tid] = sb;
    __syncthreads();
    for (int s = 128; s > 0; s >>= 1) {
        if (tid < s) red[tid] += red[tid + s];
        __syncthreads();
    }
    if (tid == 0) biasAll[o] = bih[o] + bhh[o] + red[0];
}

// ---------------------------------------------------------------------------
// Encoder GCN (reduced): Y[t, n*2+f] = norm_n * sum_j A_nj * norm_j * x[j,f]
// blockIdx.x = frame*512 + t ; 128 threads. Output bf16 [row][128], pad = 0.
// ---------------------------------------------------------------------------
__global__ __launch_bounds__(128) void gcn_enc_y(
    const float* x, const float* adj, unsigned short* Y)
{
    __shared__ float sA[N_][N_];
    __shared__ float sx[N_][2];
    __shared__ float snorm[N_];

    int frame = blockIdx.x >> 9;
    int t = blockIdx.x & 511;
    const float* xf = x + (long)frame * PRED_SZ + (long)t * 120;
    const float* af = adj + (long)frame * ADJ_SZ + (long)t * 3600;
    int tid = threadIdx.x;

    for (int l = tid; l < N_ * N_; l += 128) {
        int i = l / N_;
        int j = l - i * N_;
        float a = af[l];
        if (i == j) a += 1.0f;
        sA[i][j] = a;
    }
    if (tid < 120) sx[tid >> 1][tid & 1] = xf[tid];
    __syncthreads();

    if (tid < N_) {
        float d = 0.0f;
        for (int j = 0; j < N_; ++j) d += sA[tid][j];
        snorm[tid] = (d > 0.0f) ? rsqrtf(d) : 0.0f;
    }
    __syncthreads();

    if (tid < 128) {
        float y = 0.0f;
        if (tid < 120) {
            int n = tid >> 1;
            int f = tid & 1;
            float s = 0.0f;
            for (int j = 0; j < N_; ++j) s += sA[n][j] * snorm[j] * sx[j][f];
            y = snorm[n] * s;
        }
        Y[(long)blockIdx.x * K2_ + tid] = f2bf(y);
    }
}

// ---------------------------------------------------------------------------
// Decoder GCN (reduced): radius graph from pred, then Y as above.
// ---------------------------------------------------------------------------
__global__ __launch_bounds__(128) void gcn_dec_y(
    const float* pred, const float* stdv, const float* meanv, unsigned short* Y)
{
    __shared__ float sA[N_][N_];
    __shared__ float sx[N_][2];   // raw pred (GCN features)
    __shared__ float dx0[N_];
    __shared__ float dx1[N_];
    __shared__ int sex[N_];
    __shared__ float snorm[N_];

    int t = blockIdx.x;
    int tid = threadIdx.x;
    const float* pr = pred + (long)t * 120;

    if (tid < 120) sx[tid >> 1][tid & 1] = pr[tid];
    if (tid < N_) {
        float vx = pr[tid * 2 + 0] * stdv[0] + meanv[0];
        float vy = pr[tid * 2 + 1] * stdv[1] + meanv[1];
        dx0[tid] = vx;
        dx1[tid] = vy;
        sex[tid] = (vx > 0.04f) && (vy > 0.04f);
    }
    __syncthreads();

    for (int l = tid; l < N_ * N_; l += 128) {
        int i = l / N_;
        int j = l - i * N_;
        float ddx = dx0[i] - dx0[j];
        float ddy = dx1[i] - dx1[j];
        float d = sqrtf(ddx * ddx + ddy * ddy);
        int conn = ((d > 0.0f) && (d < 10.0f)) || (i == j);
        float a = (sex[i] && sex[j] && conn) ? 1.0f : 0.0f;
        if (i == j) a += 1.0f;     // GCN self-loop on top of radius graph
        sA[i][j] = a;
    }
    __syncthreads();

    if (tid < N_) {
        float d = 0.0f;
        for (int j = 0; j < N_; ++j) d += sA[tid][j];
        snorm[tid] = (d > 0.0f) ? rsqrtf(d) : 0.0f;
    }
    __syncthreads();

    if (tid < 128) {
        float y = 0.0f;
        if (tid < 120) {
            int n = tid >> 1;
            int f = tid & 1;
            float s = 0.0f;
            for (int j = 0; j < N_; ++j) s += sA[n][j] * snorm[j] * sx[j][f];
            y = snorm[n] * s;
        }
        Y[(long)t * K2_ + tid] = f2bf(y);
    }
}

// ---------------------------------------------------------------------------
// 32x32-tile MFMA GEMM: 4 waves, each wave one 16x16 quadrant.
// Double-buffered LDS (ONE barrier per K-iter) + 2-deep register prefetch.
// BT=1: B stored [Nc][K]; BT=0: B stored [K][Nc].
// mode 2: Cbf = bf16(relu(acc + bias1)); mode 3: Cf = acc + bias1.
// ---------------------------------------------------------------------------
template<int BT>
__global__ __launch_bounds__(256) void gemm32(
    const unsigned short* Abf, const unsigned short* Bb,
    const float* bias1, float* Cf, unsigned short* Cbf,
    int M, int Nc, int K, int mode)
{
    __shared__ unsigned short As[2][32 * LDSK];
    __shared__ unsigned short Bs[2][32 * LDSK];

    int tid = threadIdx.x;
    int wave = tid >> 6;
    int wt = wave >> 1, wj = wave & 1;
    int lane = tid & 63;
    int quad = lane >> 4;
    int l16 = lane & 15;
    int row0 = blockIdx.y * 32;
    int col0 = blockIdx.x * 32;

    f4 acc = {0.f, 0.f, 0.f, 0.f};
    const ushort4 zu = make_ushort4(0, 0, 0, 0);

    int sr = tid >> 3;          // 0..31
    int sko = (tid & 7) * 4;    // 0..28

    auto loadA = [&](int k0, ushort4& v) {
        int gm = row0 + sr, gk = k0 + sko;
        v = zu;
        if (gm < M && gk + 4 <= K) v = *(const ushort4*)&Abf[(long)gm * K + gk];
    };
    auto loadB = [&](int k0, ushort4& v) {
        v = zu;
        if (BT) {
            int gn = col0 + sr, gk = k0 + sko;
            if (gn < Nc && gk + 4 <= K) v = *(const ushort4*)&Bb[(long)gn * K + gk];
        } else {
            int gk = k0 + sr;            // k index within tile
            int gn0 = col0 + sko;        // n offset
            if (gk < K) {
                if (gn0 + 4 <= Nc) {
                    v = *(const ushort4*)&Bb[(long)gk * Nc + gn0];
                } else {
                    unsigned short tmp[4] = {0, 0, 0, 0};
                    for (int i = 0; i < 4; ++i)
                        if (gn0 + i < Nc) tmp[i] = Bb[(long)gk * Nc + gn0 + i];
                    v = make_ushort4(tmp[0], tmp[1], tmp[2], tmp[3]);
                }
            }
        }
    };

    int niter = (K + 31) / 32;
    ushort4 a0, b0, a1 = zu, b1 = zu, a2 = zu, b2 = zu;
    loadA(0, a0);
    loadB(0, b0);
    if (niter > 1) { loadA(32, a1); loadB(32, b1); }

    for (int it = 0; it < niter; ++it) {
        if (it + 2 < niter) {
            loadA((it + 2) * 32, a2);
            loadB((it + 2) * 32, b2);
        }
        int bf = it & 1;
        *(ushort4*)&As[bf][sr * LDSK + sko] = a0;
        if (BT) {
            *(ushort4*)&Bs[bf][sr * LDSK + sko] = b0;
        } else {
            Bs[bf][(sko + 0) * LDSK + sr] = b0.x;
            Bs[bf][(sko + 1) * LDSK + sr] = b0.y;
            Bs[bf][(sko + 2) * LDSK + sr] = b0.z;
            Bs[bf][(sko + 3) * LDSK + sr] = b0.w;
        }
        __syncthreads();

        bf8 fa = *(const bf8*)&As[bf][(wt * 16 + l16) * LDSK + quad * 8];
        bf8 fb = *(const bf8*)&Bs[bf][(wj * 16 + l16) * LDSK + quad * 8];
        acc = __builtin_amdgcn_mfma_f32_16x16x32_bf16(fa, fb, acc, 0, 0, 0);

        a0 = a1; a1 = a2; b0 = b1; b1 = b2;
    }

    int gn = col0 + wj * 16 + l16;
    if (gn < Nc) {
        float bsv = bias1[gn];
        #pragma unroll
        for (int r = 0; r < 4; ++r) {
            int gm = row0 + wt * 16 + quad * 4 + r;
            if (gm >= M) continue;
            float v = acc[r] + bsv;
            long idx = (long)gm * Nc + gn;
            if (mode == 2) {
                if (v < 0.0f) v = 0.0f;
                Cbf[idx] = f2bf(v);
            } else {
                Cf[idx] = v;
            }
        }
    }
}

// ---------------------------------------------------------------------------
// Fused h@Whh^T + LSTM pointwise, 256 blocks; double-buffered LDS (one
// barrier per K-iter) + 2-deep register prefetch.
// Block tile 32t x 32j x 4 gates; wave (wt,wj) computes all 4 gates for its
// 16x16 (t,j) cell -> LSTM epilogue thread-local.
// ---------------------------------------------------------------------------
__global__ __launch_bounds__(256) void whh_lstm_k(
    const unsigned short* hprev, const unsigned short* Whh_bf,
    const float* pregates, float* c, unsigned short* hnew)
{
    __shared__ unsigned short As[2][32 * LDSK];
    __shared__ unsigned short Bs[2][128 * LDSK];

    int tid = threadIdx.x;
    int wave = tid >> 6;
    int wt = wave >> 1, wj = wave & 1;
    int lane = tid & 63;
    int quad = lane >> 4;
    int l16 = lane & 15;
    int j0 = blockIdx.x * 32;
    int row0 = blockIdx.y * 32;

    int sr = tid >> 3;          // 0..31
    int sko = (tid & 7) * 4;    // 0..28
    int br = tid >> 1;          // 0..127  (gate = br>>5, jj = br&31)
    int bko = (tid & 1) * 16;   // 0 or 16
    long browbase = (long)((br >> 5) * H_ + j0 + (br & 31)) * H_;
    long arow = (long)(row0 + sr) * H_;

    f4 acc[4];
    #pragma unroll
    for (int g = 0; g < 4; ++g) acc[g] = f4{0.f, 0.f, 0.f, 0.f};

    ushort4 pa0, pa1, pa2 = make_ushort4(0, 0, 0, 0);
    uint4 q00, q01, q10, q11, q20 = uint4{0,0,0,0}, q21 = uint4{0,0,0,0};

    pa0 = *(const ushort4*)&hprev[arow + sko];
    q00 = *(const uint4*)&Whh_bf[browbase + bko];
    q01 = *(const uint4*)&Whh_bf[browbase + bko + 8];
    pa1 = *(const ushort4*)&hprev[arow + 32 + sko];
    q10 = *(const uint4*)&Whh_bf[browbase + 32 + bko];
    q11 = *(const uint4*)&Whh_bf[browbase + 32 + bko + 8];

    for (int it = 0; it < 16; ++it) {          // 16 = H_/32
        if (it + 2 < 16) {
            int kn = (it + 2) * 32;
            pa2 = *(const ushort4*)&hprev[arow + kn + sko];
            q20 = *(const uint4*)&Whh_bf[browbase + kn + bko];
            q21 = *(const uint4*)&Whh_bf[browbase + kn + bko + 8];
        }
        int bf = it & 1;
        *(ushort4*)&As[bf][sr * LDSK + sko] = pa0;
        *(uint4*)&Bs[bf][br * LDSK + bko]     = q00;
        *(uint4*)&Bs[bf][br * LDSK + bko + 8] = q01;
        __syncthreads();

        bf8 fa = *(const bf8*)&As[bf][(wt * 16 + l16) * LDSK + quad * 8];
        #pragma unroll
        for (int g = 0; g < 4; ++g) {
            bf8 fb = *(const bf8*)&Bs[bf][(g * 32 + wj * 16 + l16) * LDSK + quad * 8];
            acc[g] = __builtin_amdgcn_mfma_f32_16x16x32_bf16(fa, fb, acc[g], 0, 0, 0);
        }

        pa0 = pa1; pa1 = pa2;
        q00 = q10; q01 = q11; q10 = q20; q11 = q21;
    }

    // epilogue: LSTM pointwise; t = row0 + wt*16 + quad*4 + r, j = j0 + wj*16 + l16
    int j = j0 + wj * 16 + l16;
    #pragma unroll
    for (int r = 0; r < 4; ++r) {
        int t = row0 + wt * 16 + quad * 4 + r;
        const float* pg = pregates + (long)t * FOURH;
        float gi = pg[j]        + acc[0][r];
        float gf = pg[512 + j]  + acc[1][r];
        float gg = pg[1024 + j] + acc[2][r];
        float go = pg[1536 + j] + acc[3][r];
        float ig = 1.0f / (1.0f + expf(-gi));
        float fg = 1.0f / (1.0f + expf(-gf));
        float g2 = tanhf(gg);
        float og = 1.0f / (1.0f + expf(-go));
        long ci = (long)t * H_ + j;
        float cn = fg * c[ci] + ig * g2;
        c[ci] = cn;
        hnew[ci] = f2bf(og * tanhf(cn));
    }
}

extern "C" void kernel_launch(void* const* d_in, const int* in_sizes, int n_in,
                              void* d_out, int out_size, void* d_ws, size_t ws_size,
                              hipStream_t stream)
{
    const float* feat  = (const float*)d_in[0];
    const float* adjin = (const float*)d_in[1];
    const float* stdv  = (const float*)d_in[2];
    const float* meanv = (const float*)d_in[3];
    const float* gcnW  = (const float*)d_in[4];
    const float* gcnb  = (const float*)d_in[5];
    const float* Wih   = (const float*)d_in[6];
    const float* Whh   = (const float*)d_in[7];
    const float* bih   = (const float*)d_in[8];
    const float* bhh   = (const float*)d_in[9];
    const float* W1    = (const float*)d_in[10];
    const float* b1    = (const float*)d_in[11];
    const float* W2    = (const float*)d_in[12];
    const float* b2    = (const float*)d_in[13];
    const float* W3    = (const float*)d_in[14];
    const float* b3    = (const float*)d_in[15];
    const float* W4    = (const float*)d_in[16];
    const float* b4    = (const float*)d_in[17];
    float* out = (float*)d_out;

    int five = (ws_size >= (size_t)31400000u) ? 1 : 0;
    int slots = five ? 5 : 1;

    float* gates   = (float*)d_ws;                       // slots * 1,048,576 f
    float* c       = gates + (long)slots * 1048576;      // 262,144 f
    float* biasAll = c + 262144;                         // 2,048 f
    unsigned short* Y       = (unsigned short*)(biasAll + 2048);  // 5*65,536 us
    unsigned short* h1_bf   = Y + 5 * 65536;             // 262,144
    unsigned short* h2_bf   = h1_bf + 262144;            // 262,144
    unsigned short* m1_bf   = h2_bf + 262144;            // 262,144
    unsigned short* m2_bf   = m1_bf + 262144;            // 526,336
    unsigned short* m3_bf   = m2_bf + 526336;            // 262,144
    unsigned short* Whh_bf  = m3_bf + 262144;            // 1,048,576
    unsigned short* W1_bf   = Whh_bf + 1048576;          // 262,144
    unsigned short* W2_bf   = W1_bf + 262144;            // 526,336
    unsigned short* W3_bf   = W2_bf + 526336;            // 526,336
    unsigned short* W4_bf   = W3_bf + 526336;            // 61,440
    unsigned short* Wih2_bf = W4_bf + 61440;             // 262,144

    // weight preprocessing (graph-safe: identical work every call)
    prep_cast_k<<<9472, 256, 0, stream>>>(Whh, W1, W2, W3, W4,
                                          Whh_bf, W1_bf, W2_bf, W3_bf, W4_bf);
    wih2_k<<<FOURH, 256, 0, stream>>>(Wih, gcnW, gcnb, bih, bhh, Wih2_bf, biasAll);
    init_k<<<1024, 256, 0, stream>>>(h1_bf, c, feat, out);

    // all 5 encoder frames' reduced GCN in one launch
    gcn_enc_y<<<5 * T_, 128, 0, stream>>>(feat, adjin, Y);
    if (five)   // batched pre-gates for all encoder steps: [2560,128] @ Wih2^T
        gemm32<1><<<dim3(64, 80), 256, 0, stream>>>(Y, Wih2_bf, biasAll,
                                                    gates, (unsigned short*)0,
                                                    5 * T_, FOURH, K2_, 3);

    for (int step = 0; step < 7; ++step) {
        float* gs;
        if (step < 5) {
            if (five) {
                gs = gates + (long)step * 1048576;
            } else {
                gs = gates;
                gemm32<1><<<dim3(64, 16), 256, 0, stream>>>(Y + (long)step * 65536,
                                                            Wih2_bf, biasAll,
                                                            gs, (unsigned short*)0,
                                                            T_, FOURH, K2_, 3);
            }
        } else {
            gs = gates;   // slot 0 free after step 0
            gcn_dec_y<<<T_, 128, 0, stream>>>(out + (long)step * PRED_SZ,
                                              stdv, meanv, Y);
            gemm32<1><<<dim3(64, 16), 256, 0, stream>>>(Y, Wih2_bf, biasAll,
                                                        gs, (unsigned short*)0,
                                                        T_, FOURH, K2_, 3);
        }

        unsigned short* hp = (step & 1) ? h2_bf : h1_bf;
        unsigned short* hn = (step & 1) ? h1_bf : h2_bf;
        whh_lstm_k<<<dim3(16, 16), 256, 0, stream>>>(hp, Whh_bf, gs, c, hn);

        // MLP: h -> 512 -> 1028 -> 512 -> 120 (pred written into out)
        gemm32<0><<<dim3(16, 16), 256, 0, stream>>>(hn, W1_bf, b1,
                                                    (float*)0, m1_bf, T_, 512, 512, 2);
        gemm32<0><<<dim3(33, 16), 256, 0, stream>>>(m1_bf, W2_bf, b2,
                                                    (float*)0, m2_bf, T_, 1028, 512, 2);
        gemm32<0><<<dim3(16, 16), 256, 0, stream>>>(m2_bf, W3_bf, b3,
                                                    (float*)0, m3_bf, T_, 512, 1028, 2);
        gemm32<0><<<dim3(4, 16), 256, 0, stream>>>(m3_bf, W4_bf, b4,
                                                   out + (long)(step + 1) * PRED_SZ,
                                                   (unsigned short*)0, T_, 120, 512, 3);
    }
}

// Round 10
// 553.532 us; speedup vs baseline: 1.7901x; 1.0395x over previous
//
#include <hip/hip_runtime.h>

#define T_ 512
#define N_ 60
#define F_ 2
#define C_ 64
#define H_ 512
#define IN_ 3840
#define FOURH 2048
#define PRED_SZ 61440
#define ADJ_SZ 1843200
#define K2_ 128    // padded reduced-K for the Wih2 GEMM (120 real + 8 zero)
#define LDSK 40    // padded LDS row stride in bf16 units (2-way conflicts only)

typedef __attribute__((ext_vector_type(8))) short bf8;
typedef __attribute__((ext_vector_type(4))) float f4;

__device__ __forceinline__ unsigned short f2bf(float f)
{
    unsigned int u = __float_as_uint(f);
    u = (u + 0x7FFFu + ((u >> 16) & 1u)) >> 16;
    return (unsigned short)u;
}

// merged weight casts + state init + frame-0 copy (one launch, segment ladder)
__global__ void prep_init_k(const float* Whh, const float* W1, const float* W2,
                            const float* W3, const float* W4, const float* feat,
                            unsigned short* Whh_bf, unsigned short* W1_bf,
                            unsigned short* W2_bf, unsigned short* W3_bf,
                            unsigned short* W4_bf,
                            unsigned short* h_bf, float* c, float* out)
{
    long i = (long)blockIdx.x * 256 + threadIdx.x;   // 10496 blocks = 2,686,976
    if (i < 1048576) { Whh_bf[i] = f2bf(Whh[i]); return; }
    i -= 1048576;
    if (i < 262144) { W1_bf[i] = f2bf(W1[i]); return; }
    i -= 262144;
    if (i < 526336) { W2_bf[i] = f2bf(W2[i]); return; }
    i -= 526336;
    if (i < 526336) { W3_bf[i] = f2bf(W3[i]); return; }
    i -= 526336;
    if (i < 61440) { W4_bf[i] = f2bf(W4[i]); return; }
    i -= 61440;
    // init segment: 262,144
    h_bf[i] = 0;
    h_bf[i + 262144] = 0;   // second ping-pong buffer (contiguous)
    c[i] = 0.0f;
    if (i < PRED_SZ) out[i] = feat[i];
}

// ---------------------------------------------------------------------------
// Wih2[o, n*2+f] = sum_c Wih[o, n*64+c] * W[f,c]   (2048 x 120, pad to 128)
// biasAll[o] = bih[o] + bhh[o] + sum_k Wih[o,k]*b[k&63]
// ---------------------------------------------------------------------------
__global__ __launch_bounds__(256) void wih2_k(
    const float* Wih, const float* W, const float* b,
    const float* bih, const float* bhh,
    unsigned short* Wih2_bf, float* biasAll)
{
    __shared__ float row[IN_];     // 3840 floats
    __shared__ float wc[2][64];
    __shared__ float bb[64];
    __shared__ float red[256];

    int o = blockIdx.x;
    int tid = threadIdx.x;

    if (tid < 128) wc[tid >> 6][tid & 63] = W[tid];   // W is [2][64] row-major
    if (tid < 64) bb[tid] = b[tid];
    for (int k = tid; k < IN_; k += 256) row[k] = Wih[(long)o * IN_ + k];
    __syncthreads();

    if (tid < 128) {
        float s = 0.0f;
        if (tid < 120) {
            int n = tid >> 1;
            int f = tid & 1;
            for (int c2 = 0; c2 < 64; ++c2) s += row[n * 64 + c2] * wc[f][c2];
        }
        Wih2_bf[(long)o * K2_ + tid] = f2bf(s);   // pad cols 120..127 = 0
    }

    float sb = 0.0f;
    for (int k = tid; k < IN_; k += 256) sb += row[k] * bb[k & 63];
    red[tid] = sb;
    __syncthreads();
    for (int s = 128; s > 0; s >>= 1) {
        if (tid < s) red[tid] += red[tid + s];
        __syncthreads();
    }
    if (tid == 0) biasAll[o] = bih[o] + bhh[o] + red[0];
}

// ---------------------------------------------------------------------------
// Encoder GCN (reduced): Y[t, n*2+f] = norm_n * sum_j A_nj * norm_j * x[j,f]
// blockIdx.x = frame*512 + t ; 128 threads. Output bf16 [row][128], pad = 0.
// ---------------------------------------------------------------------------
__global__ __launch_bounds__(128) void gcn_enc_y(
    const float* x, const float* adj, unsigned short* Y)
{
    __shared__ float sA[N_][N_];
    __shared__ float sx[N_][2];
    __shared__ float snorm[N_];

    int frame = blockIdx.x >> 9;
    int t = blockIdx.x & 511;
    const float* xf = x + (long)frame * PRED_SZ + (long)t * 120;
    const float* af = adj + (long)frame * ADJ_SZ + (long)t * 3600;
    int tid = threadIdx.x;

    for (int l = tid; l < N_ * N_; l += 128) {
        int i = l / N_;
        int j = l - i * N_;
        float a = af[l];
        if (i == j) a += 1.0f;
        sA[i][j] = a;
    }
    if (tid < 120) sx[tid >> 1][tid & 1] = xf[tid];
    __syncthreads();

    if (tid < N_) {
        float d = 0.0f;
        for (int j = 0; j < N_; ++j) d += sA[tid][j];
        snorm[tid] = (d > 0.0f) ? rsqrtf(d) : 0.0f;
    }
    __syncthreads();

    if (tid < 128) {
        float y = 0.0f;
        if (tid < 120) {
            int n = tid >> 1;
            int f = tid & 1;
            float s = 0.0f;
            for (int j = 0; j < N_; ++j) s += sA[n][j] * snorm[j] * sx[j][f];
            y = snorm[n] * s;
        }
        Y[(long)blockIdx.x * K2_ + tid] = f2bf(y);
    }
}

// ---------------------------------------------------------------------------
// Decoder GCN (reduced): radius graph from pred, then Y as above.
// ---------------------------------------------------------------------------
__global__ __launch_bounds__(128) void gcn_dec_y(
    const float* pred, const float* stdv, const float* meanv, unsigned short* Y)
{
    __shared__ float sA[N_][N_];
    __shared__ float sx[N_][2];   // raw pred (GCN features)
    __shared__ float dx0[N_];
    __shared__ float dx1[N_];
    __shared__ int sex[N_];
    __shared__ float snorm[N_];

    int t = blockIdx.x;
    int tid = threadIdx.x;
    const float* pr = pred + (long)t * 120;

    if (tid < 120) sx[tid >> 1][tid & 1] = pr[tid];
    if (tid < N_) {
        float vx = pr[tid * 2 + 0] * stdv[0] + meanv[0];
        float vy = pr[tid * 2 + 1] * stdv[1] + meanv[1];
        dx0[tid] = vx;
        dx1[tid] = vy;
        sex[tid] = (vx > 0.04f) && (vy > 0.04f);
    }
    __syncthreads();

    for (int l = tid; l < N_ * N_; l += 128) {
        int i = l / N_;
        int j = l - i * N_;
        float ddx = dx0[i] - dx0[j];
        float ddy = dx1[i] - dx1[j];
        float d = sqrtf(ddx * ddx + ddy * ddy);
        int conn = ((d > 0.0f) && (d < 10.0f)) || (i == j);
        float a = (sex[i] && sex[j] && conn) ? 1.0f : 0.0f;
        if (i == j) a += 1.0f;     // GCN self-loop on top of radius graph
        sA[i][j] = a;
    }
    __syncthreads();

    if (tid < N_) {
        float d = 0.0f;
        for (int j = 0; j < N_; ++j) d += sA[tid][j];
        snorm[tid] = (d > 0.0f) ? rsqrtf(d) : 0.0f;
    }
    __syncthreads();

    if (tid < 128) {
        float y = 0.0f;
        if (tid < 120) {
            int n = tid >> 1;
            int f = tid & 1;
            float s = 0.0f;
            for (int j = 0; j < N_; ++j) s += sA[n][j] * snorm[j] * sx[j][f];
            y = snorm[n] * s;
        }
        Y[(long)t * K2_ + tid] = f2bf(y);
    }
}

// ---------------------------------------------------------------------------
// 32x32-tile MFMA GEMM, B stored [K][Nc] (MLP layers).
// Double-buffered LDS (one barrier per K-iter) + 2-deep register prefetch.
// mode 2: Cbf = bf16(relu(acc + bias1)); mode 3: Cf = acc + bias1.
// ---------------------------------------------------------------------------
__global__ __launch_bounds__(256) void mlp_gemm(
    const unsigned short* Abf, const unsigned short* Bb,
    const float* bias1, float* Cf, unsigned short* Cbf,
    int M, int Nc, int K, int mode)
{
    __shared__ unsigned short As[2][32 * LDSK];
    __shared__ unsigned short Bs[2][32 * LDSK];

    int tid = threadIdx.x;
    int wave = tid >> 6;
    int wt = wave >> 1, wj = wave & 1;
    int lane = tid & 63;
    int quad = lane >> 4;
    int l16 = lane & 15;
    int row0 = blockIdx.y * 32;
    int col0 = blockIdx.x * 32;

    f4 acc = {0.f, 0.f, 0.f, 0.f};
    const ushort4 zu = make_ushort4(0, 0, 0, 0);

    int sr = tid >> 3;          // 0..31
    int sko = (tid & 7) * 4;    // 0..28

    auto loadA = [&](int k0, ushort4& v) {
        int gm = row0 + sr, gk = k0 + sko;
        v = zu;
        if (gm < M && gk + 4 <= K) v = *(const ushort4*)&Abf[(long)gm * K + gk];
    };
    auto loadB = [&](int k0, ushort4& v) {
        int gk = k0 + sr;            // k index within tile
        int gn0 = col0 + sko;        // n offset
        v = zu;
        if (gk < K) {
            if (gn0 + 4 <= Nc) {
                v = *(const ushort4*)&Bb[(long)gk * Nc + gn0];
            } else {
                unsigned short tmp[4] = {0, 0, 0, 0};
                for (int i = 0; i < 4; ++i)
                    if (gn0 + i < Nc) tmp[i] = Bb[(long)gk * Nc + gn0 + i];
                v = make_ushort4(tmp[0], tmp[1], tmp[2], tmp[3]);
            }
        }
    };

    int niter = (K + 31) / 32;
    ushort4 a0, b0, a1 = zu, b1 = zu, a2 = zu, b2 = zu;
    loadA(0, a0);
    loadB(0, b0);
    if (niter > 1) { loadA(32, a1); loadB(32, b1); }

    for (int it = 0; it < niter; ++it) {
        if (it + 2 < niter) {
            loadA((it + 2) * 32, a2);
            loadB((it + 2) * 32, b2);
        }
        int bf = it & 1;
        *(ushort4*)&As[bf][sr * LDSK + sko] = a0;
        Bs[bf][(sko + 0) * LDSK + sr] = b0.x;
        Bs[bf][(sko + 1) * LDSK + sr] = b0.y;
        Bs[bf][(sko + 2) * LDSK + sr] = b0.z;
        Bs[bf][(sko + 3) * LDSK + sr] = b0.w;
        __syncthreads();

        bf8 fa = *(const bf8*)&As[bf][(wt * 16 + l16) * LDSK + quad * 8];
        bf8 fb = *(const bf8*)&Bs[bf][(wj * 16 + l16) * LDSK + quad * 8];
        acc = __builtin_amdgcn_mfma_f32_16x16x32_bf16(fa, fb, acc, 0, 0, 0);

        a0 = a1; a1 = a2; b0 = b1; b1 = b2;
    }

    int gn = col0 + wj * 16 + l16;
    if (gn < Nc) {
        float bsv = bias1[gn];
        #pragma unroll
        for (int r = 0; r < 4; ++r) {
            int gm = row0 + wt * 16 + quad * 4 + r;
            if (gm >= M) continue;
            float v = acc[r] + bsv;
            long idx = (long)gm * Nc + gn;
            if (mode == 2) {
                if (v < 0.0f) v = 0.0f;
                Cbf[idx] = f2bf(v);
            } else {
                Cf[idx] = v;
            }
        }
    }
}

// ---------------------------------------------------------------------------
// Fully fused gates + LSTM: gates = Y@Wih2^T + h@Whh^T + biasAll, then LSTM.
// 20 pipelined K-iters: it 0..3 over Y (K2_=128), it 4..19 over h (H_=512).
// 256 blocks (16 j x 16 t); block tile 32t x 32j x 4 gates; wave (wt,wj)
// computes all 4 gates for its 16x16 cell -> LSTM epilogue thread-local.
// Double-buffered LDS (one barrier/iter) + 2-deep register prefetch.
// ---------------------------------------------------------------------------
__global__ __launch_bounds__(256) void whh_lstm_k(
    const unsigned short* hprev, const unsigned short* Whh_bf,
    const unsigned short* Yf, const unsigned short* Wih2_bf,
    const float* biasAll, float* c, unsigned short* hnew)
{
    __shared__ unsigned short As[2][32 * LDSK];
    __shared__ unsigned short Bs[2][128 * LDSK];

    int tid = threadIdx.x;
    int wave = tid >> 6;
    int wt = wave >> 1, wj = wave & 1;
    int lane = tid & 63;
    int quad = lane >> 4;
    int l16 = lane & 15;
    int j0 = blockIdx.x * 32;
    int row0 = blockIdx.y * 32;

    int sr = tid >> 3;          // 0..31
    int sko = (tid & 7) * 4;    // 0..28
    int br = tid >> 1;          // 0..127  (gate = br>>5, jj = br&31)
    int bko = (tid & 1) * 16;   // 0 or 16
    long brow = (long)((br >> 5) * H_ + j0 + (br & 31));
    long bb_w = brow * H_;      // Whh row base (bf16 elems)
    long bb_y = brow * K2_;     // Wih2 row base
    long ar_h = (long)(row0 + sr) * H_;
    long ar_y = (long)(row0 + sr) * K2_;

    f4 acc[4];
    #pragma unroll
    for (int g = 0; g < 4; ++g) acc[g] = f4{0.f, 0.f, 0.f, 0.f};

    auto loadT = [&](int it, ushort4& a, uint4& q0, uint4& q1) {
        if (it < 4) {
            int k = it * 32;
            a  = *(const ushort4*)&Yf[ar_y + k + sko];
            q0 = *(const uint4*)&Wih2_bf[bb_y + k + bko];
            q1 = *(const uint4*)&Wih2_bf[bb_y + k + bko + 8];
        } else {
            int k = (it - 4) * 32;
            a  = *(const ushort4*)&hprev[ar_h + k + sko];
            q0 = *(const uint4*)&Whh_bf[bb_w + k + bko];
            q1 = *(const uint4*)&Whh_bf[bb_w + k + bko + 8];
        }
    };

    ushort4 a0, a1, a2 = make_ushort4(0, 0, 0, 0);
    uint4 q00, q01, q10, q11, q20 = uint4{0,0,0,0}, q21 = uint4{0,0,0,0};
    loadT(0, a0, q00, q01);
    loadT(1, a1, q10, q11);

    for (int it = 0; it < 20; ++it) {
        if (it + 2 < 20) loadT(it + 2, a2, q20, q21);
        int bf = it & 1;
        *(ushort4*)&As[bf][sr * LDSK + sko] = a0;
        *(uint4*)&Bs[bf][br * LDSK + bko]     = q00;
        *(uint4*)&Bs[bf][br * LDSK + bko + 8] = q01;
        __syncthreads();

        bf8 fa = *(const bf8*)&As[bf][(wt * 16 + l16) * LDSK + quad * 8];
        #pragma unroll
        for (int g = 0; g < 4; ++g) {
            bf8 fb = *(const bf8*)&Bs[bf][(g * 32 + wj * 16 + l16) * LDSK + quad * 8];
            acc[g] = __builtin_amdgcn_mfma_f32_16x16x32_bf16(fa, fb, acc[g], 0, 0, 0);
        }

        a0 = a1; a1 = a2;
        q00 = q10; q01 = q11; q10 = q20; q11 = q21;
    }

    // epilogue: LSTM pointwise; t = row0 + wt*16 + quad*4 + r, j = j0 + wj*16 + l16
    int j = j0 + wj * 16 + l16;
    float b_i = biasAll[j];
    float b_f = biasAll[512 + j];
    float b_g = biasAll[1024 + j];
    float b_o = biasAll[1536 + j];
    #pragma unroll
    for (int r = 0; r < 4; ++r) {
        int t = row0 + wt * 16 + quad * 4 + r;
        float gi = acc[0][r] + b_i;
        float gf = acc[1][r] + b_f;
        float gg = acc[2][r] + b_g;
        float go = acc[3][r] + b_o;
        float ig = 1.0f / (1.0f + expf(-gi));
        float fg = 1.0f / (1.0f + expf(-gf));
        float g2 = tanhf(gg);
        float og = 1.0f / (1.0f + expf(-go));
        long ci = (long)t * H_ + j;
        float cn = fg * c[ci] + ig * g2;
        c[ci] = cn;
        hnew[ci] = f2bf(og * tanhf(cn));
    }
}

extern "C" void kernel_launch(void* const* d_in, const int* in_sizes, int n_in,
                              void* d_out, int out_size, void* d_ws, size_t ws_size,
                              hipStream_t stream)
{
    const float* feat  = (const float*)d_in[0];
    const float* adjin = (const float*)d_in[1];
    const float* stdv  = (const float*)d_in[2];
    const float* meanv = (const float*)d_in[3];
    const float* gcnW  = (const float*)d_in[4];
    const float* gcnb  = (const float*)d_in[5];
    const float* Wih   = (const float*)d_in[6];
    const float* Whh   = (const float*)d_in[7];
    const float* bih   = (const float*)d_in[8];
    const float* bhh   = (const float*)d_in[9];
    const float* W1    = (const float*)d_in[10];
    const float* b1    = (const float*)d_in[11];
    const float* W2    = (const float*)d_in[12];
    const float* b2    = (const float*)d_in[13];
    const float* W3    = (const float*)d_in[14];
    const float* b3    = (const float*)d_in[15];
    const float* W4    = (const float*)d_in[16];
    const float* b4    = (const float*)d_in[17];
    float* out = (float*)d_out;

    // ws layout (~7.5 MB total; no gating needed)
    float* c       = (float*)d_ws;                       // 262,144 f
    float* biasAll = c + 262144;                         // 2,048 f
    unsigned short* Y       = (unsigned short*)(biasAll + 2048);  // 5*65,536 us
    unsigned short* h1_bf   = Y + 5 * 65536;             // 262,144
    unsigned short* h2_bf   = h1_bf + 262144;            // 262,144
    unsigned short* m1_bf   = h2_bf + 262144;            // 262,144
    unsigned short* m2_bf   = m1_bf + 262144;            // 526,336
    unsigned short* m3_bf   = m2_bf + 526336;            // 262,144
    unsigned short* Whh_bf  = m3_bf + 262144;            // 1,048,576
    unsigned short* W1_bf   = Whh_bf + 1048576;          // 262,144
    unsigned short* W2_bf   = W1_bf + 262144;            // 526,336
    unsigned short* W3_bf   = W2_bf + 526336;            // 526,336
    unsigned short* W4_bf   = W3_bf + 526336;            // 61,440
    unsigned short* Wih2_bf = W4_bf + 61440;             // 262,144

    // weight preprocessing + state init (graph-safe: identical work every call)
    prep_init_k<<<10496, 256, 0, stream>>>(Whh, W1, W2, W3, W4, feat,
                                           Whh_bf, W1_bf, W2_bf, W3_bf, W4_bf,
                                           h1_bf, c, out);
    wih2_k<<<FOURH, 256, 0, stream>>>(Wih, gcnW, gcnb, bih, bhh, Wih2_bf, biasAll);

    // all 5 encoder frames' reduced GCN in one launch
    gcn_enc_y<<<5 * T_, 128, 0, stream>>>(feat, adjin, Y);

    for (int step = 0; step < 7; ++step) {
        const unsigned short* Yf;
        if (step < 5) {
            Yf = Y + (long)step * 65536;
        } else {
            gcn_dec_y<<<T_, 128, 0, stream>>>(out + (long)step * PRED_SZ,
                                              stdv, meanv, Y);
            Yf = Y;   // frame-0 slot reused (free after step 0)
        }

        unsigned short* hp = (step & 1) ? h2_bf : h1_bf;
        unsigned short* hn = (step & 1) ? h1_bf : h2_bf;
        // gates = Yf@Wih2^T + hp@Whh^T + biasAll  -> LSTM -> hn, c
        whh_lstm_k<<<dim3(16, 16), 256, 0, stream>>>(hp, Whh_bf, Yf, Wih2_bf,
                                                     biasAll, c, hn);

        // MLP: h -> 512 -> 1028 -> 512 -> 120 (pred written into out)
        mlp_gemm<<<dim3(16, 16), 256, 0, stream>>>(hn, W1_bf, b1,
                                                   (float*)0, m1_bf, T_, 512, 512, 2);
        mlp_gemm<<<dim3(33, 16), 256, 0, stream>>>(m1_bf, W2_bf, b2,
                                                   (float*)0, m2_bf, T_, 1028, 512, 2);
        mlp_gemm<<<dim3(16, 16), 256, 0, stream>>>(m2_bf, W3_bf, b3,
                                                   (float*)0, m3_bf, T_, 512, 1028, 2);
        mlp_gemm<<<dim3(4, 16), 256, 0, stream>>>(m3_bf, W4_bf, b4,
                                                  out + (long)(step + 1) * PRED_SZ,
                                                  (unsigned short*)0, T_, 120, 512, 3);
    }
}

// Round 11
// 374.379 us; speedup vs baseline: 2.6468x; 1.4785x over previous
//
#include <hip/hip_runtime.h>

#define T_ 512
#define N_ 60
#define F_ 2
#define C_ 64
#define H_ 512
#define IN_ 3840
#define FOURH 2048
#define PRED_SZ 61440
#define ADJ_SZ 1843200
#define K2_ 128    // padded reduced-K for the Wih2 GEMM (120 real + 8 zero)
#define LDSK 40    // padded LDS row stride in bf16 units (2-way conflicts only)
#define HSLOT 262144   // one h slot (512*512 bf16)

typedef __attribute__((ext_vector_type(8))) short bf8;
typedef __attribute__((ext_vector_type(4))) float f4;

__device__ __forceinline__ unsigned short f2bf(float f)
{
    unsigned int u = __float_as_uint(f);
    u = (u + 0x7FFFu + ((u >> 16) & 1u)) >> 16;
    return (unsigned short)u;
}

// merged weight casts + state init + frame-0 copy (one launch, segment ladder)
__global__ void prep_init_k(const float* Whh, const float* W1, const float* W2,
                            const float* W3, const float* W4, const float* feat,
                            unsigned short* Whh_bf, unsigned short* W1_bf,
                            unsigned short* W2_bf, unsigned short* W3_bf,
                            unsigned short* W4_bf,
                            unsigned short* hAll, float* c, float* out)
{
    long i = (long)blockIdx.x * 256 + threadIdx.x;   // 10496 blocks = 2,686,976
    if (i < 1048576) { Whh_bf[i] = f2bf(Whh[i]); return; }
    i -= 1048576;
    if (i < 262144) { W1_bf[i] = f2bf(W1[i]); return; }
    i -= 262144;
    if (i < 526336) { W2_bf[i] = f2bf(W2[i]); return; }
    i -= 526336;
    if (i < 526336) { W3_bf[i] = f2bf(W3[i]); return; }
    i -= 526336;
    if (i < 61440) { W4_bf[i] = f2bf(W4[i]); return; }
    i -= 61440;
    // init segment: 262,144  (hAll slot 0 = initial h = 0; slots 1..7 are
    // fully written by whh steps before any read)
    hAll[i] = 0;
    c[i] = 0.0f;
    if (i < PRED_SZ) out[i] = feat[i];
}

// ---------------------------------------------------------------------------
// Wih2[o, n*2+f] = sum_c Wih[o, n*64+c] * W[f,c]   (2048 x 120, pad to 128)
// biasAll[o] = bih[o] + bhh[o] + sum_k Wih[o,k]*b[k&63]
// ---------------------------------------------------------------------------
__global__ __launch_bounds__(256) void wih2_k(
    const float* Wih, const float* W, const float* b,
    const float* bih, const float* bhh,
    unsigned short* Wih2_bf, float* biasAll)
{
    __shared__ float row[IN_];     // 3840 floats
    __shared__ float wc[2][64];
    __shared__ float bb[64];
    __shared__ float red[256];

    int o = blockIdx.x;
    int tid = threadIdx.x;

    if (tid < 128) wc[tid >> 6][tid & 63] = W[tid];   // W is [2][64] row-major
    if (tid < 64) bb[tid] = b[tid];
    for (int k = tid; k < IN_; k += 256) row[k] = Wih[(long)o * IN_ + k];
    __syncthreads();

    if (tid < 128) {
        float s = 0.0f;
        if (tid < 120) {
            int n = tid >> 1;
            int f = tid & 1;
            for (int c2 = 0; c2 < 64; ++c2) s += row[n * 64 + c2] * wc[f][c2];
        }
        Wih2_bf[(long)o * K2_ + tid] = f2bf(s);   // pad cols 120..127 = 0
    }

    float sb = 0.0f;
    for (int k = tid; k < IN_; k += 256) sb += row[k] * bb[k & 63];
    red[tid] = sb;
    __syncthreads();
    for (int s = 128; s > 0; s >>= 1) {
        if (tid < s) red[tid] += red[tid + s];
        __syncthreads();
    }
    if (tid == 0) biasAll[o] = bih[o] + bhh[o] + red[0];
}

// ---------------------------------------------------------------------------
// Encoder GCN (reduced): Y[t, n*2+f] = norm_n * sum_j A_nj * norm_j * x[j,f]
// blockIdx.x = frame*512 + t ; 128 threads. Output bf16 [row][128], pad = 0.
// ---------------------------------------------------------------------------
__global__ __launch_bounds__(128) void gcn_enc_y(
    const float* x, const float* adj, unsigned short* Y)
{
    __shared__ float sA[N_][N_];
    __shared__ float sx[N_][2];
    __shared__ float snorm[N_];

    int frame = blockIdx.x >> 9;
    int t = blockIdx.x & 511;
    const float* xf = x + (long)frame * PRED_SZ + (long)t * 120;
    const float* af = adj + (long)frame * ADJ_SZ + (long)t * 3600;
    int tid = threadIdx.x;

    for (int l = tid; l < N_ * N_; l += 128) {
        int i = l / N_;
        int j = l - i * N_;
        float a = af[l];
        if (i == j) a += 1.0f;
        sA[i][j] = a;
    }
    if (tid < 120) sx[tid >> 1][tid & 1] = xf[tid];
    __syncthreads();

    if (tid < N_) {
        float d = 0.0f;
        for (int j = 0; j < N_; ++j) d += sA[tid][j];
        snorm[tid] = (d > 0.0f) ? rsqrtf(d) : 0.0f;
    }
    __syncthreads();

    if (tid < 128) {
        float y = 0.0f;
        if (tid < 120) {
            int n = tid >> 1;
            int f = tid & 1;
            float s = 0.0f;
            for (int j = 0; j < N_; ++j) s += sA[n][j] * snorm[j] * sx[j][f];
            y = snorm[n] * s;
        }
        Y[(long)blockIdx.x * K2_ + tid] = f2bf(y);
    }
}

// ---------------------------------------------------------------------------
// Decoder GCN (reduced): radius graph from pred, then Y as above.
// ---------------------------------------------------------------------------
__global__ __launch_bounds__(128) void gcn_dec_y(
    const float* pred, const float* stdv, const float* meanv, unsigned short* Y)
{
    __shared__ float sA[N_][N_];
    __shared__ float sx[N_][2];   // raw pred (GCN features)
    __shared__ float dx0[N_];
    __shared__ float dx1[N_];
    __shared__ int sex[N_];
    __shared__ float snorm[N_];

    int t = blockIdx.x;
    int tid = threadIdx.x;
    const float* pr = pred + (long)t * 120;

    if (tid < 120) sx[tid >> 1][tid & 1] = pr[tid];
    if (tid < N_) {
        float vx = pr[tid * 2 + 0] * stdv[0] + meanv[0];
        float vy = pr[tid * 2 + 1] * stdv[1] + meanv[1];
        dx0[tid] = vx;
        dx1[tid] = vy;
        sex[tid] = (vx > 0.04f) && (vy > 0.04f);
    }
    __syncthreads();

    for (int l = tid; l < N_ * N_; l += 128) {
        int i = l / N_;
        int j = l - i * N_;
        float ddx = dx0[i] - dx0[j];
        float ddy = dx1[i] - dx1[j];
        float d = sqrtf(ddx * ddx + ddy * ddy);
        int conn = ((d > 0.0f) && (d < 10.0f)) || (i == j);
        float a = (sex[i] && sex[j] && conn) ? 1.0f : 0.0f;
        if (i == j) a += 1.0f;     // GCN self-loop on top of radius graph
        sA[i][j] = a;
    }
    __syncthreads();

    if (tid < N_) {
        float d = 0.0f;
        for (int j = 0; j < N_; ++j) d += sA[tid][j];
        snorm[tid] = (d > 0.0f) ? rsqrtf(d) : 0.0f;
    }
    __syncthreads();

    if (tid < 128) {
        float y = 0.0f;
        if (tid < 120) {
            int n = tid >> 1;
            int f = tid & 1;
            float s = 0.0f;
            for (int j = 0; j < N_; ++j) s += sA[n][j] * snorm[j] * sx[j][f];
            y = snorm[n] * s;
        }
        Y[(long)t * K2_ + tid] = f2bf(y);
    }
}

// ---------------------------------------------------------------------------
// 32x32-tile MFMA GEMM, B stored [K][Nc] (MLP layers).
// Double-buffered LDS (one barrier per K-iter) + 2-deep register prefetch.
// mode 2: Cbf = bf16(relu(acc + bias1)); mode 3: Cf = acc + bias1.
// ---------------------------------------------------------------------------
__global__ __launch_bounds__(256) void mlp_gemm(
    const unsigned short* Abf, const unsigned short* Bb,
    const float* bias1, float* Cf, unsigned short* Cbf,
    int M, int Nc, int K, int mode)
{
    __shared__ unsigned short As[2][32 * LDSK];
    __shared__ unsigned short Bs[2][32 * LDSK];

    int tid = threadIdx.x;
    int wave = tid >> 6;
    int wt = wave >> 1, wj = wave & 1;
    int lane = tid & 63;
    int quad = lane >> 4;
    int l16 = lane & 15;
    int row0 = blockIdx.y * 32;
    int col0 = blockIdx.x * 32;

    f4 acc = {0.f, 0.f, 0.f, 0.f};
    const ushort4 zu = make_ushort4(0, 0, 0, 0);

    int sr = tid >> 3;          // 0..31
    int sko = (tid & 7) * 4;    // 0..28

    auto loadA = [&](int k0, ushort4& v) {
        int gm = row0 + sr, gk = k0 + sko;
        v = zu;
        if (gm < M && gk + 4 <= K) v = *(const ushort4*)&Abf[(long)gm * K + gk];
    };
    auto loadB = [&](int k0, ushort4& v) {
        int gk = k0 + sr;            // k index within tile
        int gn0 = col0 + sko;        // n offset
        v = zu;
        if (gk < K) {
            if (gn0 + 4 <= Nc) {
                v = *(const ushort4*)&Bb[(long)gk * Nc + gn0];
            } else {
                unsigned short tmp[4] = {0, 0, 0, 0};
                for (int i = 0; i < 4; ++i)
                    if (gn0 + i < Nc) tmp[i] = Bb[(long)gk * Nc + gn0 + i];
                v = make_ushort4(tmp[0], tmp[1], tmp[2], tmp[3]);
            }
        }
    };

    int niter = (K + 31) / 32;
    ushort4 a0, b0, a1 = zu, b1 = zu, a2 = zu, b2 = zu;
    loadA(0, a0);
    loadB(0, b0);
    if (niter > 1) { loadA(32, a1); loadB(32, b1); }

    for (int it = 0; it < niter; ++it) {
        if (it + 2 < niter) {
            loadA((it + 2) * 32, a2);
            loadB((it + 2) * 32, b2);
        }
        int bf = it & 1;
        *(ushort4*)&As[bf][sr * LDSK + sko] = a0;
        Bs[bf][(sko + 0) * LDSK + sr] = b0.x;
        Bs[bf][(sko + 1) * LDSK + sr] = b0.y;
        Bs[bf][(sko + 2) * LDSK + sr] = b0.z;
        Bs[bf][(sko + 3) * LDSK + sr] = b0.w;
        __syncthreads();

        bf8 fa = *(const bf8*)&As[bf][(wt * 16 + l16) * LDSK + quad * 8];
        bf8 fb = *(const bf8*)&Bs[bf][(wj * 16 + l16) * LDSK + quad * 8];
        acc = __builtin_amdgcn_mfma_f32_16x16x32_bf16(fa, fb, acc, 0, 0, 0);

        a0 = a1; a1 = a2; b0 = b1; b1 = b2;
    }

    int gn = col0 + wj * 16 + l16;
    if (gn < Nc) {
        float bsv = bias1[gn];
        #pragma unroll
        for (int r = 0; r < 4; ++r) {
            int gm = row0 + wt * 16 + quad * 4 + r;
            if (gm >= M) continue;
            float v = acc[r] + bsv;
            long idx = (long)gm * Nc + gn;
            if (mode == 2) {
                if (v < 0.0f) v = 0.0f;
                Cbf[idx] = f2bf(v);
            } else {
                Cf[idx] = v;
            }
        }
    }
}

// ---------------------------------------------------------------------------
// Batched W1 over h slots {1,2,3,4,7}: M = 2560 rows, A-row indirection.
// grid (16, 80); K = 512, Nc = 512; out = m1 (bf16 relu).
// ---------------------------------------------------------------------------
__global__ __launch_bounds__(256) void mlp_w1b(
    const unsigned short* hAll, const unsigned short* Bb,
    const float* bias1, unsigned short* Cbf)
{
    __shared__ unsigned short As[2][32 * LDSK];
    __shared__ unsigned short Bs[2][32 * LDSK];

    int tid = threadIdx.x;
    int wave = tid >> 6;
    int wt = wave >> 1, wj = wave & 1;
    int lane = tid & 63;
    int quad = lane >> 4;
    int l16 = lane & 15;
    int row0 = blockIdx.y * 32;
    int col0 = blockIdx.x * 32;

    f4 acc = {0.f, 0.f, 0.f, 0.f};
    int sr = tid >> 3;
    int sko = (tid & 7) * 4;

    int gr = row0 + sr;                 // 0..2559
    int sidx = gr >> 9;                 // 0..4
    int slot = (sidx < 4) ? (sidx + 1) : 7;
    const unsigned short* arow = hAll + (long)slot * HSLOT + (long)(gr & 511) * H_;

    auto loadA = [&](int k0, ushort4& v) {
        v = *(const ushort4*)&arow[k0 + sko];
    };
    auto loadB = [&](int k0, ushort4& v) {
        v = *(const ushort4*)&Bb[(long)(k0 + sr) * 512 + col0 + sko];
    };

    ushort4 a0, b0, a1, b1, a2 = make_ushort4(0,0,0,0), b2 = a2;
    loadA(0, a0); loadB(0, b0);
    loadA(32, a1); loadB(32, b1);

    for (int it = 0; it < 16; ++it) {   // K = 512
        if (it + 2 < 16) { loadA((it + 2) * 32, a2); loadB((it + 2) * 32, b2); }
        int bf = it & 1;
        *(ushort4*)&As[bf][sr * LDSK + sko] = a0;
        Bs[bf][(sko + 0) * LDSK + sr] = b0.x;
        Bs[bf][(sko + 1) * LDSK + sr] = b0.y;
        Bs[bf][(sko + 2) * LDSK + sr] = b0.z;
        Bs[bf][(sko + 3) * LDSK + sr] = b0.w;
        __syncthreads();

        bf8 fa = *(const bf8*)&As[bf][(wt * 16 + l16) * LDSK + quad * 8];
        bf8 fb = *(const bf8*)&Bs[bf][(wj * 16 + l16) * LDSK + quad * 8];
        acc = __builtin_amdgcn_mfma_f32_16x16x32_bf16(fa, fb, acc, 0, 0, 0);

        a0 = a1; a1 = a2; b0 = b1; b1 = b2;
    }

    int gn = col0 + wj * 16 + l16;
    float bsv = bias1[gn];
    #pragma unroll
    for (int r = 0; r < 4; ++r) {
        int gm = row0 + wt * 16 + quad * 4 + r;
        float v = acc[r] + bsv;
        if (v < 0.0f) v = 0.0f;
        Cbf[(long)gm * 512 + gn] = f2bf(v);
    }
}

// ---------------------------------------------------------------------------
// Batched W4: A = m3 (2560 x 512), Nc = 120; output row gr -> out frame
// {1,2,3,4,7}[gr>>9], row gr&511. grid (4, 80).
// ---------------------------------------------------------------------------
__global__ __launch_bounds__(256) void mlp_w4b(
    const unsigned short* Abf, const unsigned short* Bb,
    const float* bias1, float* out)
{
    __shared__ unsigned short As[2][32 * LDSK];
    __shared__ unsigned short Bs[2][32 * LDSK];

    int tid = threadIdx.x;
    int wave = tid >> 6;
    int wt = wave >> 1, wj = wave & 1;
    int lane = tid & 63;
    int quad = lane >> 4;
    int l16 = lane & 15;
    int row0 = blockIdx.y * 32;
    int col0 = blockIdx.x * 32;

    f4 acc = {0.f, 0.f, 0.f, 0.f};
    const ushort4 zu = make_ushort4(0, 0, 0, 0);
    int sr = tid >> 3;
    int sko = (tid & 7) * 4;

    auto loadA = [&](int k0, ushort4& v) {
        v = *(const ushort4*)&Abf[(long)(row0 + sr) * 512 + k0 + sko];
    };
    auto loadB = [&](int k0, ushort4& v) {
        int gn0 = col0 + sko;
        v = zu;
        if (gn0 + 4 <= 120) {
            v = *(const ushort4*)&Bb[(long)(k0 + sr) * 120 + gn0];
        } else {
            unsigned short tmp[4] = {0, 0, 0, 0};
            for (int i = 0; i < 4; ++i)
                if (gn0 + i < 120) tmp[i] = Bb[(long)(k0 + sr) * 120 + gn0 + i];
            v = make_ushort4(tmp[0], tmp[1], tmp[2], tmp[3]);
        }
    };

    ushort4 a0, b0, a1, b1, a2 = zu, b2 = zu;
    loadA(0, a0); loadB(0, b0);
    loadA(32, a1); loadB(32, b1);

    for (int it = 0; it < 16; ++it) {   // K = 512
        if (it + 2 < 16) { loadA((it + 2) * 32, a2); loadB((it + 2) * 32, b2); }
        int bf = it & 1;
        *(ushort4*)&As[bf][sr * LDSK + sko] = a0;
        Bs[bf][(sko + 0) * LDSK + sr] = b0.x;
        Bs[bf][(sko + 1) * LDSK + sr] = b0.y;
        Bs[bf][(sko + 2) * LDSK + sr] = b0.z;
        Bs[bf][(sko + 3) * LDSK + sr] = b0.w;
        __syncthreads();

        bf8 fa = *(const bf8*)&As[bf][(wt * 16 + l16) * LDSK + quad * 8];
        bf8 fb = *(const bf8*)&Bs[bf][(wj * 16 + l16) * LDSK + quad * 8];
        acc = __builtin_amdgcn_mfma_f32_16x16x32_bf16(fa, fb, acc, 0, 0, 0);

        a0 = a1; a1 = a2; b0 = b1; b1 = b2;
    }

    int gn = col0 + wj * 16 + l16;
    if (gn < 120) {
        float bsv = bias1[gn];
        #pragma unroll
        for (int r = 0; r < 4; ++r) {
            int gm = row0 + wt * 16 + quad * 4 + r;
            int sidx = gm >> 9;
            int frame = (sidx < 4) ? (sidx + 1) : 7;
            out[(long)frame * PRED_SZ + (long)(gm & 511) * 120 + gn] = acc[r] + bsv;
        }
    }
}

// ---------------------------------------------------------------------------
// Fully fused gates + LSTM: gates = Y@Wih2^T + h@Whh^T + biasAll, then LSTM.
// 20 pipelined K-iters: it 0..3 over Y (K2_=128), it 4..19 over h (H_=512).
// 256 blocks (16 j x 16 t); wave (wt,wj) computes all 4 gates for its 16x16
// cell -> LSTM epilogue thread-local. Double-buffered LDS + 2-deep prefetch.
// ---------------------------------------------------------------------------
__global__ __launch_bounds__(256) void whh_lstm_k(
    const unsigned short* hprev, const unsigned short* Whh_bf,
    const unsigned short* Yf, const unsigned short* Wih2_bf,
    const float* biasAll, float* c, unsigned short* hnew)
{
    __shared__ unsigned short As[2][32 * LDSK];
    __shared__ unsigned short Bs[2][128 * LDSK];

    int tid = threadIdx.x;
    int wave = tid >> 6;
    int wt = wave >> 1, wj = wave & 1;
    int lane = tid & 63;
    int quad = lane >> 4;
    int l16 = lane & 15;
    int j0 = blockIdx.x * 32;
    int row0 = blockIdx.y * 32;

    int sr = tid >> 3;          // 0..31
    int sko = (tid & 7) * 4;    // 0..28
    int br = tid >> 1;          // 0..127  (gate = br>>5, jj = br&31)
    int bko = (tid & 1) * 16;   // 0 or 16
    long brow = (long)((br >> 5) * H_ + j0 + (br & 31));
    long bb_w = brow * H_;      // Whh row base (bf16 elems)
    long bb_y = brow * K2_;     // Wih2 row base
    long ar_h = (long)(row0 + sr) * H_;
    long ar_y = (long)(row0 + sr) * K2_;

    f4 acc[4];
    #pragma unroll
    for (int g = 0; g < 4; ++g) acc[g] = f4{0.f, 0.f, 0.f, 0.f};

    auto loadT = [&](int it, ushort4& a, uint4& q0, uint4& q1) {
        if (it < 4) {
            int k = it * 32;
            a  = *(const ushort4*)&Yf[ar_y + k + sko];
            q0 = *(const uint4*)&Wih2_bf[bb_y + k + bko];
            q1 = *(const uint4*)&Wih2_bf[bb_y + k + bko + 8];
        } else {
            int k = (it - 4) * 32;
            a  = *(const ushort4*)&hprev[ar_h + k + sko];
            q0 = *(const uint4*)&Whh_bf[bb_w + k + bko];
            q1 = *(const uint4*)&Whh_bf[bb_w + k + bko + 8];
        }
    };

    ushort4 a0, a1, a2 = make_ushort4(0, 0, 0, 0);
    uint4 q00, q01, q10, q11, q20 = uint4{0,0,0,0}, q21 = uint4{0,0,0,0};
    loadT(0, a0, q00, q01);
    loadT(1, a1, q10, q11);

    for (int it = 0; it < 20; ++it) {
        if (it + 2 < 20) loadT(it + 2, a2, q20, q21);
        int bf = it & 1;
        *(ushort4*)&As[bf][sr * LDSK + sko] = a0;
        *(uint4*)&Bs[bf][br * LDSK + bko]     = q00;
        *(uint4*)&Bs[bf][br * LDSK + bko + 8] = q01;
        __syncthreads();

        bf8 fa = *(const bf8*)&As[bf][(wt * 16 + l16) * LDSK + quad * 8];
        #pragma unroll
        for (int g = 0; g < 4; ++g) {
            bf8 fb = *(const bf8*)&Bs[bf][(g * 32 + wj * 16 + l16) * LDSK + quad * 8];
            acc[g] = __builtin_amdgcn_mfma_f32_16x16x32_bf16(fa, fb, acc[g], 0, 0, 0);
        }

        a0 = a1; a1 = a2;
        q00 = q10; q01 = q11; q10 = q20; q11 = q21;
    }

    int j = j0 + wj * 16 + l16;
    float b_i = biasAll[j];
    float b_f = biasAll[512 + j];
    float b_g = biasAll[1024 + j];
    float b_o = biasAll[1536 + j];
    #pragma unroll
    for (int r = 0; r < 4; ++r) {
        int t = row0 + wt * 16 + quad * 4 + r;
        float gi = acc[0][r] + b_i;
        float gf = acc[1][r] + b_f;
        float gg = acc[2][r] + b_g;
        float go = acc[3][r] + b_o;
        float ig = 1.0f / (1.0f + expf(-gi));
        float fg = 1.0f / (1.0f + expf(-gf));
        float g2 = tanhf(gg);
        float og = 1.0f / (1.0f + expf(-go));
        long ci = (long)t * H_ + j;
        float cn = fg * c[ci] + ig * g2;
        c[ci] = cn;
        hnew[ci] = f2bf(og * tanhf(cn));
    }
}

extern "C" void kernel_launch(void* const* d_in, const int* in_sizes, int n_in,
                              void* d_out, int out_size, void* d_ws, size_t ws_size,
                              hipStream_t stream)
{
    const float* feat  = (const float*)d_in[0];
    const float* adjin = (const float*)d_in[1];
    const float* stdv  = (const float*)d_in[2];
    const float* meanv = (const float*)d_in[3];
    const float* gcnW  = (const float*)d_in[4];
    const float* gcnb  = (const float*)d_in[5];
    const float* Wih   = (const float*)d_in[6];
    const float* Whh   = (const float*)d_in[7];
    const float* bih   = (const float*)d_in[8];
    const float* bhh   = (const float*)d_in[9];
    const float* W1    = (const float*)d_in[10];
    const float* b1    = (const float*)d_in[11];
    const float* W2    = (const float*)d_in[12];
    const float* b2    = (const float*)d_in[13];
    const float* W3    = (const float*)d_in[14];
    const float* b3    = (const float*)d_in[15];
    const float* W4    = (const float*)d_in[16];
    const float* b4    = (const float*)d_in[17];
    float* out = (float*)d_out;

    // ws layout (~21 MB total)
    float* c       = (float*)d_ws;                       // 262,144 f
    float* biasAll = c + 262144;                         // 2,048 f
    unsigned short* Y       = (unsigned short*)(biasAll + 2048);  // 5*65,536 us
    unsigned short* hAll    = Y + 5 * 65536;             // 8 * 262,144 us
    unsigned short* m1      = hAll + 8 * HSLOT;          // 2560*512 = 1,310,720
    unsigned short* m2      = m1 + 1310720;              // 2560*1028 = 2,631,680
    unsigned short* m3      = m2 + 2631680;              // 1,310,720
    unsigned short* Whh_bf  = m3 + 1310720;              // 1,048,576
    unsigned short* W1_bf   = Whh_bf + 1048576;          // 262,144
    unsigned short* W2_bf   = W1_bf + 262144;            // 526,336
    unsigned short* W3_bf   = W2_bf + 526336;            // 526,336
    unsigned short* W4_bf   = W3_bf + 526336;            // 61,440
    unsigned short* Wih2_bf = W4_bf + 61440;             // 262,144

    // weight preprocessing + state init (graph-safe: identical work every call)
    prep_init_k<<<10496, 256, 0, stream>>>(Whh, W1, W2, W3, W4, feat,
                                           Whh_bf, W1_bf, W2_bf, W3_bf, W4_bf,
                                           hAll, c, out);
    wih2_k<<<FOURH, 256, 0, stream>>>(Wih, gcnW, gcnb, bih, bhh, Wih2_bf, biasAll);
    gcn_enc_y<<<5 * T_, 128, 0, stream>>>(feat, adjin, Y);

    // --- LSTM spine, encoder steps 0..4 (MLPs deferred; h saved per step) ---
    for (int s = 0; s < 5; ++s)
        whh_lstm_k<<<dim3(16, 16), 256, 0, stream>>>(hAll + (long)s * HSLOT,
                                                     Whh_bf, Y + (long)s * 65536,
                                                     Wih2_bf, biasAll, c,
                                                     hAll + (long)(s + 1) * HSLOT);

    // --- critical tail: MLP(4) -> Y(5) -> whh(5) -> MLP(5) -> Y(6) -> whh(6) ---
    for (int s = 4; s <= 5; ++s) {
        const unsigned short* hs = hAll + (long)(s + 1) * HSLOT;
        mlp_gemm<<<dim3(16, 16), 256, 0, stream>>>(hs, W1_bf, b1,
                                                   (float*)0, m1, T_, 512, 512, 2);
        mlp_gemm<<<dim3(33, 16), 256, 0, stream>>>(m1, W2_bf, b2,
                                                   (float*)0, m2, T_, 1028, 512, 2);
        mlp_gemm<<<dim3(16, 16), 256, 0, stream>>>(m2, W3_bf, b3,
                                                   (float*)0, m3, T_, 512, 1028, 2);
        mlp_gemm<<<dim3(4, 16), 256, 0, stream>>>(m3, W4_bf, b4,
                                                  out + (long)(s + 1) * PRED_SZ,
                                                  (unsigned short*)0, T_, 120, 512, 3);
        gcn_dec_y<<<T_, 128, 0, stream>>>(out + (long)(s + 1) * PRED_SZ,
                                          stdv, meanv, Y);
        whh_lstm_k<<<dim3(16, 16), 256, 0, stream>>>(hAll + (long)(s + 1) * HSLOT,
                                                     Whh_bf, Y, Wih2_bf, biasAll, c,
                                                     hAll + (long)(s + 2) * HSLOT);
    }

    // --- batched MLP for off-critical-path steps {0,1,2,3,6}: M = 2560 ---
    mlp_w1b<<<dim3(16, 80), 256, 0, stream>>>(hAll, W1_bf, b1, m1);
    mlp_gemm<<<dim3(33, 80), 256, 0, stream>>>(m1, W2_bf, b2,
                                               (float*)0, m2, 2560, 1028, 512, 2);
    mlp_gemm<<<dim3(16, 80), 256, 0, stream>>>(m2, W3_bf, b3,
                                               (float*)0, m3, 2560, 512, 1028, 2);
    mlp_w4b<<<dim3(4, 80), 256, 0, stream>>>(m3, W4_bf, b4, out);
}